// Round 10
// baseline (278.520 us; speedup 1.0000x reference)
//
#include <hip/hip_runtime.h>
#include <math.h>

// ---------------------------------------------------------------------------
// AttentionNet weighted-anchor aggregator.
//   x:  (8, 448, 448, 3) f32
//   wp3:(8, 6, 4, 14, 14) f32   wp4:(8, 6, 4, 7, 7) f32   wp5:(8, 9, 4, 4, 4) f32
//   out:(32, 224, 224, 3) f32 = sum over 21 configs of
//        resize_bilinear( einsum('bkij,bihjwc->bkhwc', w, patches), 224,224 )
//
// Phase 0a: init_tables — normalized zero-padded 4-tap weights + i0.
// Phase 0b: transpose_w — weights to [cfg][b][grid][k0..k3] float4.
// Phase 0c: build_xpad — zero-padded x copy [8][448][768][3] (cols +128/+192).
//           Removes ALL masks/clamps/cndmask from the agg inner loop (was
//           ~6.5 of ~20.5 VALU inst per (i,j) visit; agg is VALU-issue-bound
//           at 60% busy). Out-of-image loads now return exact 0 from pad.
// Phase A : agg body — strided-pair mapping, k-interleaved [px][k0..k3] agg,
//           mask-free loads from xpad.
// Phase B : rz body — 2 k-planes/thread, uint4 taps, compile-time unrolled.
//           PLANE-PAIR-PER-XCD swizzle: pair = blockIdx%8 so (under round-
//           robin block->XCD) XCD x reads only planes b==x — the same L2
//           that agg (b = local&7) wrote them to. Cuts L2 re-fetch ~8x.
// OVERLAP : G0={0..14} G1={15..18} G2={19..20};
//     agg(G0->A); fused(agg G1->B, rz G0<-A);
//     fused(agg G2->A, rz G1<-B); rz(G2<-A)
//   Runtime ws check; serial schedule fallback (also xpad-based).
// ---------------------------------------------------------------------------

#define BATCH 8
#define KK 4
#define OUT_HW 224
#define IMG_HW 448
#define NCFG 21

#define XP_W 768
#define XP_ROWF (XP_W * 3)                      // 2304 floats per padded row

#define WTBL_BYTES (NCFG * 2 * OUT_HW * 16)     // 150528
#define ITBL_BYTES (NCFG * 2 * OUT_HW * 4)      // 37632
#define WT_OFF_BYTES (WTBL_BYTES + ITBL_BYTES)  // 188160
#define WT_F4 12912                             // 8 * (6*196 + 6*49 + 9*16)
#define XPAD_OFF_BYTES (WT_OFF_BYTES + WT_F4 * 16)          // 394752
#define XPAD_FLOATS_IMG (IMG_HW * XP_ROWF)                  // 1032192
#define XPAD_BYTES (BATCH * XPAD_FLOATS_IMG * 4)            // 33030144
#define AGG_OFF_BYTES (XPAD_OFF_BYTES + XPAD_BYTES)         // 33424896

#define RZ_GRID (14 * 14 * 16)                  // 3136 resize blocks

typedef float v2f __attribute__((ext_vector_type(2)));

// Compile-time cfg geometry (== host double-precision construction; margins
// to int-truncation boundaries are >=0.05 so this is exact).
static constexpr int cKH[NCFG]  = {74,60,49,93,76,62, 148,120,98,186,152,124,
                                   235,192,156,296,241,197,373,304,248};
static constexpr int cKW[NCFG]  = {49,60,74,62,76,93, 98,120,148,124,152,186,
                                   156,192,235,197,241,296,248,304,373};
static constexpr int cMTH[NCFG] = {2,2,2,2,2,2, 2,2,2,2,2,2, 3,2,2,3,3,2,4,3,3};
static constexpr int cMTW[NCFG] = {2,2,2,2,2,2, 2,2,2,2,2,2, 2,2,3,2,3,3,3,3,4};

__host__ __device__ constexpr int ckwp(int c) { return cKW[c] + (cKW[c] & 1); }
// uint2-offset of cfg c's region within its group (layout [b][px][k]).
__host__ __device__ constexpr long cwsoff(int c, int g) {
    long o = 0;
    for (int k = g; k < c; ++k) o += (long)cKH[k] * ckwp(k) * (BATCH * KK);
    return o;
}

struct ACfg {              // agg view of a config
    int kh, kw, kwp, p0, p1;
    int layer;             // 0=p3, 1=p4, 2=p5
    int ns;                // base-slot count per row (strided pairing)
    int wt_off;            // float4 offset of transposed weights
    int ws_off;            // uint2 offset in agg region
    int block_start;
    int blocks_per_img;    // ceil(kh*ns/256)
};

struct AggArgs {
    ACfg e[NCFG];
    int n;
};

struct TablesArgs { int kh[NCFG]; int kw[NCFG]; };

struct TrArgs {
    int layer[NCFG];
    int anchor[NCFG];
    int gsz[NCFG];
    int wt_off[NCFG];
};

struct F3 { float a, b, c; };

__device__ inline unsigned int bf16_rne(float f) {
    unsigned int u = __float_as_uint(f);
    return (u + 0x7fffu + ((u >> 16) & 1u)) >> 16;
}

// ---------------------------------------------------------------------------
// Phase 0a: tap tables. jax.image.resize('bilinear', antialias=True).
// ---------------------------------------------------------------------------
__global__ __launch_bounds__(256) void init_tables(float4* __restrict__ wtbl,
                                                   int* __restrict__ itbl,
                                                   TablesArgs t) {
    int cfg = blockIdx.x >> 1;
    int dim = blockIdx.x & 1;
    int o = threadIdx.x;
    if (o >= OUT_HW) return;
    int n = dim ? t.kw[cfg] : t.kh[cfg];

    float inv = (float)(1.0 / ((double)OUT_HW / (double)n));
    float ks  = inv > 1.f ? inv : 1.f;
    float rks = 1.f / ks;
    float sf  = ((float)o + 0.5f) * inv - 0.5f;
    int i0 = (int)ceilf(sf - ks);  if (i0 < 0) i0 = 0;
    int i1 = (int)floorf(sf + ks); if (i1 > n - 1) i1 = n - 1;
    float sum = 0.f;
    for (int i = i0; i <= i1; ++i) {
        float v = 1.f - fabsf((float)i - sf) * rks;
        sum += (v > 0.f ? v : 0.f);
    }
    float rsum = 1.f / sum;
    float w[4];
#pragma unroll
    for (int d = 0; d < 4; ++d) {
        int i = i0 + d;
        float v = 0.f;
        if (i <= i1) {
            v = 1.f - fabsf((float)i - sf) * rks;
            v = (v > 0.f ? v : 0.f) * rsum;
        }
        w[d] = v;
    }
    int idx = cfg * (2 * OUT_HW) + dim * OUT_HW + o;
    wtbl[idx] = make_float4(w[0], w[1], w[2], w[3]);
    itbl[idx] = i0;
}

// ---------------------------------------------------------------------------
// Phase 0b: transpose weights (B,A,K,gh,gw) -> per cfg [b][g][k0..k3] float4.
// ---------------------------------------------------------------------------
__global__ __launch_bounds__(256) void transpose_w(
        const float* __restrict__ wp3, const float* __restrict__ wp4,
        const float* __restrict__ wp5, float4* __restrict__ wT, TrArgs t) {
    int cfg = blockIdx.x;
    int b = blockIdx.y;
    int gsz = t.gsz[cfg];
    const float* base;
    int A;
    if (t.layer[cfg] == 0)      { base = wp3; A = 6; }
    else if (t.layer[cfg] == 1) { base = wp4; A = 6; }
    else                        { base = wp5; A = 9; }
    const float* src = base + (size_t)(b * A + t.anchor[cfg]) * (KK * gsz);
    for (int g = threadIdx.x; g < gsz; g += 256) {
        wT[t.wt_off[cfg] + b * gsz + g] =
            make_float4(src[0 * gsz + g], src[1 * gsz + g],
                        src[2 * gsz + g], src[3 * gsz + g]);
    }
}

// ---------------------------------------------------------------------------
// Phase 0c: padded x copy. Rows are never out of range (agg keeps ilo/ihi),
// so only columns pad: xpad[b][row][col][ch], col in [0,768), interior
// cols [128,576) = x[col-128], rest exact 0.
// ---------------------------------------------------------------------------
__global__ __launch_bounds__(256) void build_xpad(
        const float* __restrict__ x, float* __restrict__ xpad) {
    int f4 = (int)blockIdx.x * 256 + (int)threadIdx.x;   // 0..2064383
    int f0 = f4 * 4;
    int b   = f0 / XPAD_FLOATS_IMG;
    int rem = f0 - b * XPAD_FLOATS_IMG;
    int row = rem / XP_ROWF;
    int cf  = rem - row * XP_ROWF;
    float4 v;
    float* vv = (float*)&v;
#pragma unroll
    for (int q = 0; q < 4; ++q) {
        int cfq = cf + q;
        int px = cfq / 3;
        int ch = cfq - px * 3;
        float val = 0.f;
        int xc = px - 128;
        if ((unsigned)xc < (unsigned)IMG_HW)
            val = x[((size_t)b * IMG_HW + row) * (IMG_HW * 3) + xc * 3 + ch];
        vv[q] = val;
    }
    *(float4*)(xpad + ((size_t)b * IMG_HW + row) * XP_ROWF + cf) = v;
}

// ---------------------------------------------------------------------------
// Agg body: strided-pair outputs (w0, w0+STRIDE) packed as v2f lanes;
// MASK-FREE loads from xpad (out-of-image -> exact 0 from pad); one min
// clamp per hoisted column offset (discarded-lane only, lands in pad).
// k-interleaved epilogue (two uint4 stores per px).
// ---------------------------------------------------------------------------
template <int GH, int GW, int STRIDE, int L2S>
__device__ inline void agg_body(const ACfg& c, int b, int h, int slot,
                                const float* __restrict__ xpb,
                                const float4* __restrict__ wlds,
                                uint2* __restrict__ agg) {
    const int w0 = (((slot >> L2S) << (L2S + 1)) | (slot & (STRIDE - 1)));
    const int w1 = w0 + STRIDE;
    const bool two = w1 < c.kw;

    v2f acc2[4][3];
#pragma unroll
    for (int k = 0; k < 4; ++k)
#pragma unroll
        for (int ch = 0; ch < 3; ++ch) { acc2[k][ch].x = 0.f; acc2[k][ch].y = 0.f; }

    const int rb = h - c.p0;
    int ilo = rb >= 0 ? 0 : (-rb + STRIDE - 1) / STRIDE;
    int ihi = (IMG_HW - 1 - rb) / STRIDE;
    if (ihi > GH - 1) ihi = GH - 1;

    const int cb = w0 - c.p1 + 128;     // padded col base, >= 5

    int cof[GW + 1];
#pragma unroll
    for (int jj = 0; jj <= GW; ++jj) {
        int col = cb + jj * STRIDE;
        if (col > XP_W - 1) col = XP_W - 1;   // discarded-lane only; pad=0
        cof[jj] = col * 3;
    }

#pragma unroll 1
    for (int i = ilo; i <= ihi; ++i) {
        const float* xr = xpb + (size_t)(rb + i * STRIDE) * XP_ROWF;
        const float4* wrow = wlds + i * GW;

        float px[GW + 1][3];
#pragma unroll
        for (int jj = 0; jj <= GW; ++jj) {
            F3 v = *(const F3*)(xr + cof[jj]);
            px[jj][0] = v.a;
            px[jj][1] = v.b;
            px[jj][2] = v.c;
        }

#pragma unroll
        for (int j = 0; j < GW; ++j) {
            float4 wk = wrow[j];
            v2f d0 = {px[j][0], px[j + 1][0]};
            v2f d1 = {px[j][1], px[j + 1][1]};
            v2f d2 = {px[j][2], px[j + 1][2]};
            v2f wv0 = {wk.x, wk.x};
            v2f wv1 = {wk.y, wk.y};
            v2f wv2 = {wk.z, wk.z};
            v2f wv3 = {wk.w, wk.w};
            acc2[0][0] = __builtin_elementwise_fma(wv0, d0, acc2[0][0]);
            acc2[0][1] = __builtin_elementwise_fma(wv0, d1, acc2[0][1]);
            acc2[0][2] = __builtin_elementwise_fma(wv0, d2, acc2[0][2]);
            acc2[1][0] = __builtin_elementwise_fma(wv1, d0, acc2[1][0]);
            acc2[1][1] = __builtin_elementwise_fma(wv1, d1, acc2[1][1]);
            acc2[1][2] = __builtin_elementwise_fma(wv1, d2, acc2[1][2]);
            acc2[2][0] = __builtin_elementwise_fma(wv2, d0, acc2[2][0]);
            acc2[2][1] = __builtin_elementwise_fma(wv2, d1, acc2[2][1]);
            acc2[2][2] = __builtin_elementwise_fma(wv2, d2, acc2[2][2]);
            acc2[3][0] = __builtin_elementwise_fma(wv3, d0, acc2[3][0]);
            acc2[3][1] = __builtin_elementwise_fma(wv3, d1, acc2[3][1]);
            acc2[3][2] = __builtin_elementwise_fma(wv3, d2, acc2[3][2]);
        }
    }

    const int npix = c.kh * c.kwp;
    size_t pb0 = (size_t)c.ws_off
               + ((size_t)b * npix + (size_t)h * c.kwp + w0) * KK;
    {
        uint4 s0, s1;
        s0.x = bf16_rne(acc2[0][0].x) | (bf16_rne(acc2[0][1].x) << 16);
        s0.y = bf16_rne(acc2[0][2].x);
        s0.z = bf16_rne(acc2[1][0].x) | (bf16_rne(acc2[1][1].x) << 16);
        s0.w = bf16_rne(acc2[1][2].x);
        s1.x = bf16_rne(acc2[2][0].x) | (bf16_rne(acc2[2][1].x) << 16);
        s1.y = bf16_rne(acc2[2][2].x);
        s1.z = bf16_rne(acc2[3][0].x) | (bf16_rne(acc2[3][1].x) << 16);
        s1.w = bf16_rne(acc2[3][2].x);
        *(uint4*)(agg + pb0)     = s0;
        *(uint4*)(agg + pb0 + 2) = s1;
    }
    if (two) {
        size_t pb1 = pb0 + (size_t)STRIDE * KK;
        uint4 s0, s1;
        s0.x = bf16_rne(acc2[0][0].y) | (bf16_rne(acc2[0][1].y) << 16);
        s0.y = bf16_rne(acc2[0][2].y);
        s0.z = bf16_rne(acc2[1][0].y) | (bf16_rne(acc2[1][1].y) << 16);
        s0.w = bf16_rne(acc2[1][2].y);
        s1.x = bf16_rne(acc2[2][0].y) | (bf16_rne(acc2[2][1].y) << 16);
        s1.y = bf16_rne(acc2[2][2].y);
        s1.z = bf16_rne(acc2[3][0].y) | (bf16_rne(acc2[3][1].y) << 16);
        s1.w = bf16_rne(acc2[3][2].y);
        *(uint4*)(agg + pb1)     = s0;
        *(uint4*)(agg + pb1 + 2) = s1;
    }
}

// ---------------------------------------------------------------------------
// Agg top (device): cfg lookup + weight staging + body dispatch.
// b = local & 7: image-per-XCD (block_start always 8-aligned).
// ---------------------------------------------------------------------------
__device__ inline void agg_top(int bid, const float* __restrict__ xpad,
                               const float4* __restrict__ wT,
                               uint2* __restrict__ agg, const AggArgs& a,
                               float4* wlds, int tid) {
    int ci = 0;
    while (ci + 1 < a.n && bid >= a.e[ci + 1].block_start) ci++;
    const ACfg c = a.e[ci];
    int local = bid - c.block_start;
    int b     = local & 7;           // image-per-XCD
    int sblk  = local >> 3;

    const int gsz = (c.layer == 0) ? 196 : (c.layer == 1) ? 49 : 16;
    for (int t = tid; t < gsz; t += 256)
        wlds[t] = wT[c.wt_off + b * gsz + t];
    __syncthreads();

    int pidx = sblk * 256 + tid;
    if (pidx >= c.kh * c.ns) return;
    int h    = pidx / c.ns;
    int slot = pidx - h * c.ns;

    const float* __restrict__ xpb = xpad + (size_t)b * XPAD_FLOATS_IMG;
    if (c.layer == 0)      agg_body<14, 14, 32, 5>(c, b, h, slot, xpb, wlds, agg);
    else if (c.layer == 1) agg_body<7, 7, 64, 6>(c, b, h, slot, xpb, wlds, agg);
    else                   agg_body<4, 4, 128, 7>(c, b, h, slot, xpb, wlds, agg);
}

__global__ __launch_bounds__(256, 3) void agg_all(
        const float* __restrict__ xpad,
        const float4* __restrict__ wT,
        uint2* __restrict__ agg,
        AggArgs a) {
    __shared__ float4 wlds[196];
    agg_top(blockIdx.x, xpad, wT, agg, a, wlds, (int)threadIdx.x);
}

// ---------------------------------------------------------------------------
// Tap micro-kernel, 2 k-planes per thread: each tap is ONE uint4 load.
// ---------------------------------------------------------------------------
template <int TH, int TW, int KH_, int KW_, int KWP_>
__device__ inline void taps_ct2(const uint2* __restrict__ pb,
                                int i0, int j0,
                                float4 wh4, float4 ww4,
                                v2f (&a)[3]) {
    const float* wh = (const float*)&wh4;
    const float* ww = (const float*)&ww4;
    uint4 v[TH][TW];
#pragma unroll
    for (int d = 0; d < TH; ++d) {
        int gi = i0 + d;
        if (gi > KH_ - 1) gi = KH_ - 1;
        const uint2* rp = pb + (size_t)gi * (KWP_ * KK);
#pragma unroll
        for (int e = 0; e < TW; ++e) {
            int gj = j0 + e;
            if (gj > KW_ - 1) gj = KW_ - 1;
            v[d][e] = *(const uint4*)(rp + gj * KK);
        }
    }
#pragma unroll
    for (int d = 0; d < TH; ++d) {
        v2f r0 = {0.f, 0.f}, r1 = {0.f, 0.f}, r2 = {0.f, 0.f};
#pragma unroll
        for (int e = 0; e < TW; ++e) {
            uint4 q = v[d][e];
            v2f c0, c1, c2;
            c0.x = __uint_as_float(q.x << 16);
            c0.y = __uint_as_float(q.z << 16);
            c1.x = __uint_as_float(q.x & 0xffff0000u);
            c1.y = __uint_as_float(q.z & 0xffff0000u);
            c2.x = __uint_as_float(q.y << 16);
            c2.y = __uint_as_float(q.w << 16);
            v2f w2 = {ww[e], ww[e]};
            r0 = __builtin_elementwise_fma(w2, c0, r0);
            r1 = __builtin_elementwise_fma(w2, c1, r1);
            r2 = __builtin_elementwise_fma(w2, c2, r2);
        }
        v2f h2 = {wh[d], wh[d]};
        a[0] = __builtin_elementwise_fma(h2, r0, a[0]);
        a[1] = __builtin_elementwise_fma(h2, r1, a[1]);
        a[2] = __builtin_elementwise_fma(h2, r2, a[2]);
    }
}

template <int C, int CEND, int CSTART>
__device__ inline void do_rounds(const uint2* __restrict__ agg,
                                 const float4* __restrict__ wlds,
                                 const int* __restrict__ ilds,
                                 int b, int kp, int tx, int ty,
                                 v2f (&a)[3]) {
    if constexpr (C < CEND) {
        constexpr int li  = C - CSTART;
        constexpr int kh  = cKH[C];
        constexpr int kw  = cKW[C];
        constexpr int kwp = ckwp(C);
        constexpr long wso = cwsoff(C, CSTART);
        float4 wh4 = wlds[li * 32 + ty];
        float4 ww4 = wlds[li * 32 + 16 + tx];
        int i0 = ilds[li * 32 + ty];
        int j0 = ilds[li * 32 + 16 + tx];
        const uint2* pb = agg + wso
                        + (size_t)b * ((size_t)kh * kwp * KK) + kp * 2;
        taps_ct2<cMTH[C], cMTW[C], kh, kw, kwp>(pb, i0, j0, wh4, ww4, a);
        do_rounds<C + 1, CEND, CSTART>(agg, wlds, ilds, b, kp, tx, ty, a);
    }
}

// ---------------------------------------------------------------------------
// rz block decomposition with plane-pair-per-XCD swizzle.
// pair = abs_bid % 8 (the XCD under round-robin dispatch); each residue
// class gets exactly 392 tiles = 2 full (b,kp) planes; b == pair matches
// the XCD that aggregated image b (agg: b = local & 7).
// ---------------------------------------------------------------------------
__device__ inline void rz_decomp(int abs_bid, int n0,
                                 int& bx, int& by, int& zz) {
    int pair = abs_bid & 7;
    int tile = (abs_bid - n0) >> 3;     // 0..391 within the class
    int q    = tile / 196;              // which plane of the pair
    int t    = tile - q * 196;
    zz = pair * 2 + q;
    by = t / 14;
    bx = t - by * 14;
}

// ---------------------------------------------------------------------------
// Resize top (device): table staging + unrolled rounds. 2 k-planes/thread.
// ---------------------------------------------------------------------------
template <int CSTART, int CEND>
__device__ inline void rz_top(const uint2* __restrict__ agg,
                              const float4* __restrict__ wtbl,
                              const int* __restrict__ itbl,
                              float* __restrict__ out, int accumulate,
                              int bx, int by, int zz, int tid,
                              float4* wlds, int* ilds) {
    constexpr int NC = CEND - CSTART;
    const int tx = tid & 15;
    const int ty = tid >> 4;
    const int xo = bx * 16 + tx;
    const int yo = by * 16 + ty;
    const int b  = zz >> 1;
    const int kp = zz & 1;

    for (int e = tid; e < NC * 32; e += 256) {
        int ci  = e >> 5;
        int r   = e & 31;
        int isW = r >> 4;
        int idx = r & 15;
        int base_o = isW ? (bx * 16) : (by * 16);
        int src = (CSTART + ci) * (2 * OUT_HW) + isW * OUT_HW + base_o + idx;
        wlds[ci * 32 + r] = wtbl[src];
        ilds[ci * 32 + r] = itbl[src];
    }
    __syncthreads();

    size_t obA = ((((size_t)(b * KK + kp * 2)) * OUT_HW + yo) * OUT_HW + xo) * 3;
    size_t obB = obA + (size_t)OUT_HW * OUT_HW * 3;

    v2f a[3];
    if (accumulate) {
        a[0].x = out[obA + 0]; a[0].y = out[obB + 0];
        a[1].x = out[obA + 1]; a[1].y = out[obB + 1];
        a[2].x = out[obA + 2]; a[2].y = out[obB + 2];
    } else {
        a[0] = v2f{0.f, 0.f}; a[1] = v2f{0.f, 0.f}; a[2] = v2f{0.f, 0.f};
    }

    do_rounds<CSTART, CEND, CSTART>(agg, wlds, ilds, b, kp, tx, ty, a);

    out[obA + 0] = a[0].x; out[obA + 1] = a[1].x; out[obA + 2] = a[2].x;
    out[obB + 0] = a[0].y; out[obB + 1] = a[1].y; out[obB + 2] = a[2].y;
}

template <int CSTART, int CEND>
__global__ __launch_bounds__(256, 4) void resize_static(
        const uint2* __restrict__ agg,
        const float4* __restrict__ wtbl,
        const int* __restrict__ itbl,
        float* __restrict__ out,
        int accumulate) {
    constexpr int NC = CEND - CSTART;
    __shared__ float4 wlds[NC * 32];
    __shared__ int    ilds[NC * 32];
    int bx, by, zz;
    rz_decomp((int)blockIdx.x, 0, bx, by, zz);
    rz_top<CSTART, CEND>(agg, wtbl, itbl, out, accumulate,
                         bx, by, zz, (int)threadIdx.x, wlds, ilds);
}

// ---------------------------------------------------------------------------
// Fused dispatch: blocks [0,nagg) run agg for the NEXT group (write aggW);
// blocks [nagg, nagg+RZ_GRID) run resize of the PREVIOUS group (read aggR).
// Regions are disjoint (double-buffered), so no intra-kernel sync needed.
// ---------------------------------------------------------------------------
template <int CSTART, int CEND>
__global__ __launch_bounds__(256, 3) void fused_k(
        const float* __restrict__ xpad,
        const float4* __restrict__ wT,
        uint2* __restrict__ aggW,
        AggArgs a, int naggBlocks,
        const uint2* __restrict__ aggR,
        const float4* __restrict__ wtbl,
        const int* __restrict__ itbl,
        float* __restrict__ out,
        int accumulate) {
    constexpr int NC = CEND - CSTART;
    __shared__ float4 wldsA[196];
    __shared__ float4 wldsR[NC * 32];
    __shared__ int    ildsR[NC * 32];
    const int tid = (int)threadIdx.x;
    if ((int)blockIdx.x < naggBlocks) {
        agg_top((int)blockIdx.x, xpad, wT, aggW, a, wldsA, tid);
    } else {
        int bx, by, zz;
        rz_decomp((int)blockIdx.x, naggBlocks, bx, by, zz);
        rz_top<CSTART, CEND>(aggR, wtbl, itbl, out, accumulate,
                             bx, by, zz, tid, wldsR, ildsR);
    }
}

// ---------------------------------------------------------------------------
// Host launch
// ---------------------------------------------------------------------------
extern "C" void kernel_launch(void* const* d_in, const int* in_sizes, int n_in,
                              void* d_out, int out_size, void* d_ws, size_t ws_size,
                              hipStream_t stream) {
    const float* x   = (const float*)d_in[0];
    const float* wp3 = (const float*)d_in[1];
    const float* wp4 = (const float*)d_in[2];
    const float* wp5 = (const float*)d_in[3];
    float* out = (float*)d_out;
    float4* wtbl = (float4*)d_ws;
    int*    itbl = (int*)((char*)d_ws + WTBL_BYTES);
    float4* wT   = (float4*)((char*)d_ws + WT_OFF_BYTES);
    float*  xpad = (float*)((char*)d_ws + XPAD_OFF_BYTES);
    uint2*  agg  = (uint2*)((char*)d_ws + AGG_OFF_BYTES);

    // Build the 21 configs exactly as the reference does (double precision).
    struct { int stride, size, nscale; double scales[3]; int gh; } layers[3] = {
        {32, 48, 2, {pow(2.0, 1.0 / 3.0), pow(2.0, 2.0 / 3.0), 0.0}, 14},
        {64, 96, 2, {pow(2.0, 1.0 / 3.0), pow(2.0, 2.0 / 3.0), 0.0}, 7},
        {128, 192, 3, {1.0, pow(2.0, 1.0 / 3.0), pow(2.0, 2.0 / 3.0)}, 4},
    };
    const double ars[3] = {0.667, 1.0, 1.5};

    struct HostCfg {
        int kh, kw, kwp, stride, p0, p1, gh, gw, layer, anchor, wt_off;
        int ns, blocks_per_img;
    } cfg[NCFG];
    TablesArgs ta;
    TrArgs tr;
    int nc = 0, wt_run = 0;
    for (int L = 0; L < 3; ++L) {
        int anchor = 0;
        for (int si = 0; si < layers[L].nscale; ++si) {
            for (int ai = 0; ai < 3; ++ai) {
                double ss = (double)layers[L].size * layers[L].scales[si];
                double sq = pow(ars[ai], 0.5);
                int kh = (int)(ss / sq);
                int kw = (int)(ss * sq);
                HostCfg& e = cfg[nc];
                e.kh = kh; e.kw = kw;
                e.kwp = kw + (kw & 1);
                e.stride = layers[L].stride;
                e.p0 = (int)ceil((double)(kh - layers[L].stride) / 2.0);
                e.p1 = (int)ceil((double)(kw - layers[L].stride) / 2.0);
                e.gh = layers[L].gh; e.gw = layers[L].gh;
                e.layer = L; e.anchor = anchor++;
                int s = e.stride;
                int q = kw / s, r = kw % s;
                e.ns = ((q + 1) / 2) * s + ((q % 2 == 0) ? r : 0);
                e.blocks_per_img = (kh * e.ns + 255) / 256;
                e.wt_off = wt_run;
                int gsz = e.gh * e.gw;
                wt_run += BATCH * gsz;
                ta.kh[nc] = kh; ta.kw[nc] = kw;
                tr.layer[nc] = L; tr.anchor[nc] = e.anchor;
                tr.gsz[nc] = gsz; tr.wt_off[nc] = e.wt_off;
                ++nc;
            }
        }
    }

    init_tables<<<NCFG * 2, 256, 0, stream>>>(wtbl, itbl, ta);
    transpose_w<<<dim3(NCFG, BATCH), 256, 0, stream>>>(wp3, wp4, wp5, wT, tr);
    build_xpad<<<(BATCH * XPAD_FLOATS_IMG / 4) / 256, 256, 0, stream>>>(x, xpad);

    auto build = [&](int gstart, int gend, AggArgs& aa) -> int {
        aa.n = 0;
        int ablocks = 0;
        size_t off = 0;
        for (int c = gstart; c < gend; ++c) {
            ACfg& lc = aa.e[aa.n++];
            lc.kh = cfg[c].kh; lc.kw = cfg[c].kw; lc.kwp = cfg[c].kwp;
            lc.p0 = cfg[c].p0; lc.p1 = cfg[c].p1;
            lc.layer = cfg[c].layer;
            lc.ns = cfg[c].ns;
            lc.wt_off = cfg[c].wt_off;
            lc.ws_off = (int)off;
            lc.block_start = ablocks;
            lc.blocks_per_img = cfg[c].blocks_per_img;
            ablocks += cfg[c].blocks_per_img * BATCH;
            off += (size_t)cfg[c].kh * cfg[c].kwp * (BATCH * KK);
        }
        return ablocks;
    };
    auto gpx = [&](int gstart, int gend) -> size_t {
        size_t p = 0;
        for (int c = gstart; c < gend; ++c)
            p += (size_t)cfg[c].kh * cfg[c].kwp;
        return p * (BATCH * KK);
    };

    // Overlap schedule: G0={0..14} G1={15..18} G2={19..20}.
    size_t pxG0 = gpx(0, 15), pxG1 = gpx(15, 19), pxG2 = gpx(19, 21);
    size_t pxA = pxG0 > pxG2 ? pxG0 : pxG2;
    size_t pxB = pxG1;
    bool can_overlap =
        (size_t)AGG_OFF_BYTES + (pxA + pxB) * sizeof(uint2) <= ws_size;

    if (can_overlap) {
        uint2* bufA = agg;
        uint2* bufB = agg + pxA;
        AggArgs a0, a1, a2;
        int n0 = build(0, 15, a0);
        int n1 = build(15, 19, a1);
        int n2 = build(19, 21, a2);

        agg_all<<<n0, 256, 0, stream>>>(xpad, wT, bufA, a0);
        fused_k<0, 15><<<n1 + RZ_GRID, 256, 0, stream>>>(
            xpad, wT, bufB, a1, n1, bufA, wtbl, itbl, out, 0);
        fused_k<15, 19><<<n2 + RZ_GRID, 256, 0, stream>>>(
            xpad, wT, bufA, a2, n2, bufB, wtbl, itbl, out, 1);
        resize_static<19, 21><<<RZ_GRID, 256, 0, stream>>>(
            bufA, wtbl, itbl, out, 1);
    } else {
        // Serial fallback: 3 groups, single buffer (still xpad-based).
        AggArgs aa;
        int nb;
        nb = build(0, 15, aa);
        agg_all<<<nb, 256, 0, stream>>>(xpad, wT, agg, aa);
        resize_static<0, 15><<<RZ_GRID, 256, 0, stream>>>(agg, wtbl, itbl, out, 0);
        nb = build(15, 19, aa);
        agg_all<<<nb, 256, 0, stream>>>(xpad, wT, agg, aa);
        resize_static<15, 19><<<RZ_GRID, 256, 0, stream>>>(agg, wtbl, itbl, out, 1);
        nb = build(19, 21, aa);
        agg_all<<<nb, 256, 0, stream>>>(xpad, wT, agg, aa);
        resize_static<19, 21><<<RZ_GRID, 256, 0, stream>>>(agg, wtbl, itbl, out, 1);
    }
    (void)in_sizes; (void)n_in; (void)out_size;
}

// Round 11
// 266.103 us; speedup vs baseline: 1.0467x; 1.0467x over previous
//
#include <hip/hip_runtime.h>
#include <math.h>

// ---------------------------------------------------------------------------
// AttentionNet weighted-anchor aggregator.
//   x:  (8, 448, 448, 3) f32
//   wp3:(8, 6, 4, 14, 14) f32   wp4:(8, 6, 4, 7, 7) f32   wp5:(8, 9, 4, 4, 4) f32
//   out:(32, 224, 224, 3) f32 = sum over 21 configs of
//        resize_bilinear( einsum('bkij,bihjwc->bkhwc', w, patches), 224,224 )
//
// Bodies = round-9 exactly (r10's xpad + plane-swizzle both regressed and are
// reverted): agg = strided-pair, masked clamped loads, k-interleaved layout;
// rz = 2 k-planes/thread uint4 taps, compile-time unrolled rounds.
//
// SCHEDULE (this round's change): r9 proved fused = max(parts) — agg G1 rode
// free under rz G0. Re-cut groups so the serial head is SMALL but FULL-WIDTH
// (r8 lesson: small head must not be per-thread-heavy/underfilled; p5 cfgs
// 12..14 give 2336 latency-light blocks):
//   H={12..14} G1={0..11} G2={15..18} G3={19..20}
//   agg(H->A); fused(agg G1->B, rz H<-A); fused(agg G2->A, rz G1<-B);
//   fused(agg G3->B, rz G2<-A); rz(G3<-B)
// Buffers: A = max(H,G2) = 69MB, B = max(G1,G3) = 47MB. Runtime ws check;
// serial 4-group fallback (same template ranges).
// ---------------------------------------------------------------------------

#define BATCH 8
#define KK 4
#define OUT_HW 224
#define IMG_HW 448
#define NCFG 21

#define WTBL_BYTES (NCFG * 2 * OUT_HW * 16)     // 150528
#define ITBL_BYTES (NCFG * 2 * OUT_HW * 4)      // 37632
#define WT_OFF_BYTES (WTBL_BYTES + ITBL_BYTES)  // 188160
#define WT_F4 12912                             // 8 * (6*196 + 6*49 + 9*16)
#define AGG_OFF_BYTES (WT_OFF_BYTES + WT_F4 * 16)  // 394752 (16B aligned)

#define RZ_GRID (14 * 14 * 16)                  // 3136 resize blocks

typedef float v2f __attribute__((ext_vector_type(2)));

// Compile-time cfg geometry (== host double-precision construction; margins
// to int-truncation boundaries are >=0.05 so this is exact).
static constexpr int cKH[NCFG]  = {74,60,49,93,76,62, 148,120,98,186,152,124,
                                   235,192,156,296,241,197,373,304,248};
static constexpr int cKW[NCFG]  = {49,60,74,62,76,93, 98,120,148,124,152,186,
                                   156,192,235,197,241,296,248,304,373};
static constexpr int cMTH[NCFG] = {2,2,2,2,2,2, 2,2,2,2,2,2, 3,2,2,3,3,2,4,3,3};
static constexpr int cMTW[NCFG] = {2,2,2,2,2,2, 2,2,2,2,2,2, 2,2,3,2,3,3,3,3,4};

__host__ __device__ constexpr int ckwp(int c) { return cKW[c] + (cKW[c] & 1); }
// uint2-offset of cfg c's region within its group (layout [b][px][k]).
__host__ __device__ constexpr long cwsoff(int c, int g) {
    long o = 0;
    for (int k = g; k < c; ++k) o += (long)cKH[k] * ckwp(k) * (BATCH * KK);
    return o;
}

struct ACfg {              // agg view of a config
    int kh, kw, kwp, p0, p1;
    int layer;             // 0=p3, 1=p4, 2=p5
    int ns;                // base-slot count per row (strided pairing)
    int wt_off;            // float4 offset of transposed weights
    int ws_off;            // uint2 offset in agg region
    int block_start;
    int blocks_per_img;    // ceil(kh*ns/256)
};

struct AggArgs {
    ACfg e[NCFG];
    int n;
};

struct TablesArgs { int kh[NCFG]; int kw[NCFG]; };

struct TrArgs {
    int layer[NCFG];
    int anchor[NCFG];
    int gsz[NCFG];
    int wt_off[NCFG];
};

struct F3 { float a, b, c; };

__device__ inline unsigned int bf16_rne(float f) {
    unsigned int u = __float_as_uint(f);
    return (u + 0x7fffu + ((u >> 16) & 1u)) >> 16;
}

// ---------------------------------------------------------------------------
// Phase 0a: tap tables. jax.image.resize('bilinear', antialias=True).
// ---------------------------------------------------------------------------
__global__ __launch_bounds__(256) void init_tables(float4* __restrict__ wtbl,
                                                   int* __restrict__ itbl,
                                                   TablesArgs t) {
    int cfg = blockIdx.x >> 1;
    int dim = blockIdx.x & 1;
    int o = threadIdx.x;
    if (o >= OUT_HW) return;
    int n = dim ? t.kw[cfg] : t.kh[cfg];

    float inv = (float)(1.0 / ((double)OUT_HW / (double)n));
    float ks  = inv > 1.f ? inv : 1.f;
    float rks = 1.f / ks;
    float sf  = ((float)o + 0.5f) * inv - 0.5f;
    int i0 = (int)ceilf(sf - ks);  if (i0 < 0) i0 = 0;
    int i1 = (int)floorf(sf + ks); if (i1 > n - 1) i1 = n - 1;
    float sum = 0.f;
    for (int i = i0; i <= i1; ++i) {
        float v = 1.f - fabsf((float)i - sf) * rks;
        sum += (v > 0.f ? v : 0.f);
    }
    float rsum = 1.f / sum;
    float w[4];
#pragma unroll
    for (int d = 0; d < 4; ++d) {
        int i = i0 + d;
        float v = 0.f;
        if (i <= i1) {
            v = 1.f - fabsf((float)i - sf) * rks;
            v = (v > 0.f ? v : 0.f) * rsum;
        }
        w[d] = v;
    }
    int idx = cfg * (2 * OUT_HW) + dim * OUT_HW + o;
    wtbl[idx] = make_float4(w[0], w[1], w[2], w[3]);
    itbl[idx] = i0;
}

// ---------------------------------------------------------------------------
// Phase 0b: transpose weights (B,A,K,gh,gw) -> per cfg [b][g][k0..k3] float4.
// ---------------------------------------------------------------------------
__global__ __launch_bounds__(256) void transpose_w(
        const float* __restrict__ wp3, const float* __restrict__ wp4,
        const float* __restrict__ wp5, float4* __restrict__ wT, TrArgs t) {
    int cfg = blockIdx.x;
    int b = blockIdx.y;
    int gsz = t.gsz[cfg];
    const float* base;
    int A;
    if (t.layer[cfg] == 0)      { base = wp3; A = 6; }
    else if (t.layer[cfg] == 1) { base = wp4; A = 6; }
    else                        { base = wp5; A = 9; }
    const float* src = base + (size_t)(b * A + t.anchor[cfg]) * (KK * gsz);
    for (int g = threadIdx.x; g < gsz; g += 256) {
        wT[t.wt_off[cfg] + b * gsz + g] =
            make_float4(src[0 * gsz + g], src[1 * gsz + g],
                        src[2 * gsz + g], src[3 * gsz + g]);
    }
}

// ---------------------------------------------------------------------------
// Agg body: strided-pair outputs (w0, w0+STRIDE) packed as v2f lanes;
// k-interleaved epilogue (two uint4 stores per px).
// ---------------------------------------------------------------------------
template <int GH, int GW, int STRIDE, int L2S>
__device__ inline void agg_body(const ACfg& c, int b, int h, int slot,
                                const float* __restrict__ xb,
                                const float4* __restrict__ wlds,
                                uint2* __restrict__ agg) {
    const int w0 = (((slot >> L2S) << (L2S + 1)) | (slot & (STRIDE - 1)));
    const int w1 = w0 + STRIDE;
    const bool two = w1 < c.kw;

    v2f acc2[4][3];
#pragma unroll
    for (int k = 0; k < 4; ++k)
#pragma unroll
        for (int ch = 0; ch < 3; ++ch) { acc2[k][ch].x = 0.f; acc2[k][ch].y = 0.f; }

    const int rb = h - c.p0;
    int ilo = rb >= 0 ? 0 : (-rb + STRIDE - 1) / STRIDE;
    int ihi = (IMG_HW - 1 - rb) / STRIDE;
    if (ihi > GH - 1) ihi = GH - 1;

    const int cb = w0 - c.p1;

    int  cof[GW + 1];
    bool ok [GW + 1];
#pragma unroll
    for (int jj = 0; jj <= GW; ++jj) {
        int col = cb + jj * STRIDE;
        ok[jj] = (unsigned)col < (unsigned)IMG_HW;
        unsigned cc = (unsigned)col;
        if (cc > (unsigned)(IMG_HW - 1)) cc = (unsigned)(IMG_HW - 1);
        cof[jj] = (int)cc * 3;
    }

#pragma unroll 1
    for (int i = ilo; i <= ihi; ++i) {
        const float* xr = xb + (size_t)(rb + i * STRIDE) * (IMG_HW * 3);
        const float4* wrow = wlds + i * GW;

        float px[GW + 1][3];
#pragma unroll
        for (int jj = 0; jj <= GW; ++jj) {
            F3 v = *(const F3*)(xr + cof[jj]);
            px[jj][0] = ok[jj] ? v.a : 0.f;
            px[jj][1] = ok[jj] ? v.b : 0.f;
            px[jj][2] = ok[jj] ? v.c : 0.f;
        }

#pragma unroll
        for (int j = 0; j < GW; ++j) {
            float4 wk = wrow[j];
            v2f d0 = {px[j][0], px[j + 1][0]};
            v2f d1 = {px[j][1], px[j + 1][1]};
            v2f d2 = {px[j][2], px[j + 1][2]};
            v2f wv0 = {wk.x, wk.x};
            v2f wv1 = {wk.y, wk.y};
            v2f wv2 = {wk.z, wk.z};
            v2f wv3 = {wk.w, wk.w};
            acc2[0][0] = __builtin_elementwise_fma(wv0, d0, acc2[0][0]);
            acc2[0][1] = __builtin_elementwise_fma(wv0, d1, acc2[0][1]);
            acc2[0][2] = __builtin_elementwise_fma(wv0, d2, acc2[0][2]);
            acc2[1][0] = __builtin_elementwise_fma(wv1, d0, acc2[1][0]);
            acc2[1][1] = __builtin_elementwise_fma(wv1, d1, acc2[1][1]);
            acc2[1][2] = __builtin_elementwise_fma(wv1, d2, acc2[1][2]);
            acc2[2][0] = __builtin_elementwise_fma(wv2, d0, acc2[2][0]);
            acc2[2][1] = __builtin_elementwise_fma(wv2, d1, acc2[2][1]);
            acc2[2][2] = __builtin_elementwise_fma(wv2, d2, acc2[2][2]);
            acc2[3][0] = __builtin_elementwise_fma(wv3, d0, acc2[3][0]);
            acc2[3][1] = __builtin_elementwise_fma(wv3, d1, acc2[3][1]);
            acc2[3][2] = __builtin_elementwise_fma(wv3, d2, acc2[3][2]);
        }
    }

    const int npix = c.kh * c.kwp;
    size_t pb0 = (size_t)c.ws_off
               + ((size_t)b * npix + (size_t)h * c.kwp + w0) * KK;
    {
        uint4 s0, s1;
        s0.x = bf16_rne(acc2[0][0].x) | (bf16_rne(acc2[0][1].x) << 16);
        s0.y = bf16_rne(acc2[0][2].x);
        s0.z = bf16_rne(acc2[1][0].x) | (bf16_rne(acc2[1][1].x) << 16);
        s0.w = bf16_rne(acc2[1][2].x);
        s1.x = bf16_rne(acc2[2][0].x) | (bf16_rne(acc2[2][1].x) << 16);
        s1.y = bf16_rne(acc2[2][2].x);
        s1.z = bf16_rne(acc2[3][0].x) | (bf16_rne(acc2[3][1].x) << 16);
        s1.w = bf16_rne(acc2[3][2].x);
        *(uint4*)(agg + pb0)     = s0;
        *(uint4*)(agg + pb0 + 2) = s1;
    }
    if (two) {
        size_t pb1 = pb0 + (size_t)STRIDE * KK;
        uint4 s0, s1;
        s0.x = bf16_rne(acc2[0][0].y) | (bf16_rne(acc2[0][1].y) << 16);
        s0.y = bf16_rne(acc2[0][2].y);
        s0.z = bf16_rne(acc2[1][0].y) | (bf16_rne(acc2[1][1].y) << 16);
        s0.w = bf16_rne(acc2[1][2].y);
        s1.x = bf16_rne(acc2[2][0].y) | (bf16_rne(acc2[2][1].y) << 16);
        s1.y = bf16_rne(acc2[2][2].y);
        s1.z = bf16_rne(acc2[3][0].y) | (bf16_rne(acc2[3][1].y) << 16);
        s1.w = bf16_rne(acc2[3][2].y);
        *(uint4*)(agg + pb1)     = s0;
        *(uint4*)(agg + pb1 + 2) = s1;
    }
}

// ---------------------------------------------------------------------------
// Agg top (device): cfg lookup + weight staging + body dispatch.
// b = local & 7: image-per-XCD (block_start always 8-aligned).
// ---------------------------------------------------------------------------
__device__ inline void agg_top(int bid, const float* __restrict__ x,
                               const float4* __restrict__ wT,
                               uint2* __restrict__ agg, const AggArgs& a,
                               float4* wlds, int tid) {
    int ci = 0;
    while (ci + 1 < a.n && bid >= a.e[ci + 1].block_start) ci++;
    const ACfg c = a.e[ci];
    int local = bid - c.block_start;
    int b     = local & 7;           // image-per-XCD
    int sblk  = local >> 3;

    const int gsz = (c.layer == 0) ? 196 : (c.layer == 1) ? 49 : 16;
    for (int t = tid; t < gsz; t += 256)
        wlds[t] = wT[c.wt_off + b * gsz + t];
    __syncthreads();

    int pidx = sblk * 256 + tid;
    if (pidx >= c.kh * c.ns) return;
    int h    = pidx / c.ns;
    int slot = pidx - h * c.ns;

    const float* __restrict__ xb = x + (size_t)b * (IMG_HW * IMG_HW * 3);
    if (c.layer == 0)      agg_body<14, 14, 32, 5>(c, b, h, slot, xb, wlds, agg);
    else if (c.layer == 1) agg_body<7, 7, 64, 6>(c, b, h, slot, xb, wlds, agg);
    else                   agg_body<4, 4, 128, 7>(c, b, h, slot, xb, wlds, agg);
}

__global__ __launch_bounds__(256, 3) void agg_all(
        const float* __restrict__ x,
        const float4* __restrict__ wT,
        uint2* __restrict__ agg,
        AggArgs a) {
    __shared__ float4 wlds[196];
    agg_top(blockIdx.x, x, wT, agg, a, wlds, (int)threadIdx.x);
}

// ---------------------------------------------------------------------------
// Tap micro-kernel, 2 k-planes per thread: each tap is ONE uint4 load.
// ---------------------------------------------------------------------------
template <int TH, int TW, int KH_, int KW_, int KWP_>
__device__ inline void taps_ct2(const uint2* __restrict__ pb,
                                int i0, int j0,
                                float4 wh4, float4 ww4,
                                v2f (&a)[3]) {
    const float* wh = (const float*)&wh4;
    const float* ww = (const float*)&ww4;
    uint4 v[TH][TW];
#pragma unroll
    for (int d = 0; d < TH; ++d) {
        int gi = i0 + d;
        if (gi > KH_ - 1) gi = KH_ - 1;
        const uint2* rp = pb + (size_t)gi * (KWP_ * KK);
#pragma unroll
        for (int e = 0; e < TW; ++e) {
            int gj = j0 + e;
            if (gj > KW_ - 1) gj = KW_ - 1;
            v[d][e] = *(const uint4*)(rp + gj * KK);
        }
    }
#pragma unroll
    for (int d = 0; d < TH; ++d) {
        v2f r0 = {0.f, 0.f}, r1 = {0.f, 0.f}, r2 = {0.f, 0.f};
#pragma unroll
        for (int e = 0; e < TW; ++e) {
            uint4 q = v[d][e];
            v2f c0, c1, c2;
            c0.x = __uint_as_float(q.x << 16);
            c0.y = __uint_as_float(q.z << 16);
            c1.x = __uint_as_float(q.x & 0xffff0000u);
            c1.y = __uint_as_float(q.z & 0xffff0000u);
            c2.x = __uint_as_float(q.y << 16);
            c2.y = __uint_as_float(q.w << 16);
            v2f w2 = {ww[e], ww[e]};
            r0 = __builtin_elementwise_fma(w2, c0, r0);
            r1 = __builtin_elementwise_fma(w2, c1, r1);
            r2 = __builtin_elementwise_fma(w2, c2, r2);
        }
        v2f h2 = {wh[d], wh[d]};
        a[0] = __builtin_elementwise_fma(h2, r0, a[0]);
        a[1] = __builtin_elementwise_fma(h2, r1, a[1]);
        a[2] = __builtin_elementwise_fma(h2, r2, a[2]);
    }
}

template <int C, int CEND, int CSTART>
__device__ inline void do_rounds(const uint2* __restrict__ agg,
                                 const float4* __restrict__ wlds,
                                 const int* __restrict__ ilds,
                                 int b, int kp, int tx, int ty,
                                 v2f (&a)[3]) {
    if constexpr (C < CEND) {
        constexpr int li  = C - CSTART;
        constexpr int kh  = cKH[C];
        constexpr int kw  = cKW[C];
        constexpr int kwp = ckwp(C);
        constexpr long wso = cwsoff(C, CSTART);
        float4 wh4 = wlds[li * 32 + ty];
        float4 ww4 = wlds[li * 32 + 16 + tx];
        int i0 = ilds[li * 32 + ty];
        int j0 = ilds[li * 32 + 16 + tx];
        const uint2* pb = agg + wso
                        + (size_t)b * ((size_t)kh * kwp * KK) + kp * 2;
        taps_ct2<cMTH[C], cMTW[C], kh, kw, kwp>(pb, i0, j0, wh4, ww4, a);
        do_rounds<C + 1, CEND, CSTART>(agg, wlds, ilds, b, kp, tx, ty, a);
    }
}

// ---------------------------------------------------------------------------
// Resize top (device): table staging + unrolled rounds. 2 k-planes/thread.
// ---------------------------------------------------------------------------
template <int CSTART, int CEND>
__device__ inline void rz_top(const uint2* __restrict__ agg,
                              const float4* __restrict__ wtbl,
                              const int* __restrict__ itbl,
                              float* __restrict__ out, int accumulate,
                              int bx, int by, int zz, int tid,
                              float4* wlds, int* ilds) {
    constexpr int NC = CEND - CSTART;
    const int tx = tid & 15;
    const int ty = tid >> 4;
    const int xo = bx * 16 + tx;
    const int yo = by * 16 + ty;
    const int b  = zz >> 1;
    const int kp = zz & 1;

    for (int e = tid; e < NC * 32; e += 256) {
        int ci  = e >> 5;
        int r   = e & 31;
        int isW = r >> 4;
        int idx = r & 15;
        int base_o = isW ? (bx * 16) : (by * 16);
        int src = (CSTART + ci) * (2 * OUT_HW) + isW * OUT_HW + base_o + idx;
        wlds[ci * 32 + r] = wtbl[src];
        ilds[ci * 32 + r] = itbl[src];
    }
    __syncthreads();

    size_t obA = ((((size_t)(b * KK + kp * 2)) * OUT_HW + yo) * OUT_HW + xo) * 3;
    size_t obB = obA + (size_t)OUT_HW * OUT_HW * 3;

    v2f a[3];
    if (accumulate) {
        a[0].x = out[obA + 0]; a[0].y = out[obB + 0];
        a[1].x = out[obA + 1]; a[1].y = out[obB + 1];
        a[2].x = out[obA + 2]; a[2].y = out[obB + 2];
    } else {
        a[0] = v2f{0.f, 0.f}; a[1] = v2f{0.f, 0.f}; a[2] = v2f{0.f, 0.f};
    }

    do_rounds<CSTART, CEND, CSTART>(agg, wlds, ilds, b, kp, tx, ty, a);

    out[obA + 0] = a[0].x; out[obA + 1] = a[1].x; out[obA + 2] = a[2].x;
    out[obB + 0] = a[0].y; out[obB + 1] = a[1].y; out[obB + 2] = a[2].y;
}

template <int CSTART, int CEND>
__global__ __launch_bounds__(256, 4) void resize_static(
        const uint2* __restrict__ agg,
        const float4* __restrict__ wtbl,
        const int* __restrict__ itbl,
        float* __restrict__ out,
        int accumulate) {
    constexpr int NC = CEND - CSTART;
    __shared__ float4 wlds[NC * 32];
    __shared__ int    ilds[NC * 32];
    rz_top<CSTART, CEND>(agg, wtbl, itbl, out, accumulate,
                         (int)blockIdx.x, (int)blockIdx.y, (int)blockIdx.z,
                         (int)threadIdx.x, wlds, ilds);
}

// ---------------------------------------------------------------------------
// Fused dispatch: blocks [0,nagg) run agg for the NEXT group (write aggW);
// blocks [nagg, nagg+RZ_GRID) run resize of the PREVIOUS group (read aggR).
// Regions are disjoint (double-buffered), so no intra-kernel sync needed.
// ---------------------------------------------------------------------------
template <int CSTART, int CEND>
__global__ __launch_bounds__(256, 3) void fused_k(
        const float* __restrict__ x,
        const float4* __restrict__ wT,
        uint2* __restrict__ aggW,
        AggArgs a, int naggBlocks,
        const uint2* __restrict__ aggR,
        const float4* __restrict__ wtbl,
        const int* __restrict__ itbl,
        float* __restrict__ out,
        int accumulate) {
    constexpr int NC = CEND - CSTART;
    __shared__ float4 wldsA[196];
    __shared__ float4 wldsR[NC * 32];
    __shared__ int    ildsR[NC * 32];
    const int tid = (int)threadIdx.x;
    if ((int)blockIdx.x < naggBlocks) {
        agg_top((int)blockIdx.x, x, wT, aggW, a, wldsA, tid);
    } else {
        int rid = (int)blockIdx.x - naggBlocks;
        int bx = rid % 14;
        int t2 = rid / 14;
        int by = t2 % 14;
        int zz = t2 / 14;
        rz_top<CSTART, CEND>(aggR, wtbl, itbl, out, accumulate,
                             bx, by, zz, tid, wldsR, ildsR);
    }
}

// ---------------------------------------------------------------------------
// Host launch
// ---------------------------------------------------------------------------
extern "C" void kernel_launch(void* const* d_in, const int* in_sizes, int n_in,
                              void* d_out, int out_size, void* d_ws, size_t ws_size,
                              hipStream_t stream) {
    const float* x   = (const float*)d_in[0];
    const float* wp3 = (const float*)d_in[1];
    const float* wp4 = (const float*)d_in[2];
    const float* wp5 = (const float*)d_in[3];
    float* out = (float*)d_out;
    float4* wtbl = (float4*)d_ws;
    int*    itbl = (int*)((char*)d_ws + WTBL_BYTES);
    float4* wT   = (float4*)((char*)d_ws + WT_OFF_BYTES);
    uint2*  agg  = (uint2*)((char*)d_ws + AGG_OFF_BYTES);

    // Build the 21 configs exactly as the reference does (double precision).
    struct { int stride, size, nscale; double scales[3]; int gh; } layers[3] = {
        {32, 48, 2, {pow(2.0, 1.0 / 3.0), pow(2.0, 2.0 / 3.0), 0.0}, 14},
        {64, 96, 2, {pow(2.0, 1.0 / 3.0), pow(2.0, 2.0 / 3.0), 0.0}, 7},
        {128, 192, 3, {1.0, pow(2.0, 1.0 / 3.0), pow(2.0, 2.0 / 3.0)}, 4},
    };
    const double ars[3] = {0.667, 1.0, 1.5};

    struct HostCfg {
        int kh, kw, kwp, stride, p0, p1, gh, gw, layer, anchor, wt_off;
        int ns, blocks_per_img;
    } cfg[NCFG];
    TablesArgs ta;
    TrArgs tr;
    int nc = 0, wt_run = 0;
    for (int L = 0; L < 3; ++L) {
        int anchor = 0;
        for (int si = 0; si < layers[L].nscale; ++si) {
            for (int ai = 0; ai < 3; ++ai) {
                double ss = (double)layers[L].size * layers[L].scales[si];
                double sq = pow(ars[ai], 0.5);
                int kh = (int)(ss / sq);
                int kw = (int)(ss * sq);
                HostCfg& e = cfg[nc];
                e.kh = kh; e.kw = kw;
                e.kwp = kw + (kw & 1);
                e.stride = layers[L].stride;
                e.p0 = (int)ceil((double)(kh - layers[L].stride) / 2.0);
                e.p1 = (int)ceil((double)(kw - layers[L].stride) / 2.0);
                e.gh = layers[L].gh; e.gw = layers[L].gh;
                e.layer = L; e.anchor = anchor++;
                int s = e.stride;
                int q = kw / s, r = kw % s;
                e.ns = ((q + 1) / 2) * s + ((q % 2 == 0) ? r : 0);
                e.blocks_per_img = (kh * e.ns + 255) / 256;
                e.wt_off = wt_run;
                int gsz = e.gh * e.gw;
                wt_run += BATCH * gsz;
                ta.kh[nc] = kh; ta.kw[nc] = kw;
                tr.layer[nc] = L; tr.anchor[nc] = e.anchor;
                tr.gsz[nc] = gsz; tr.wt_off[nc] = e.wt_off;
                ++nc;
            }
        }
    }

    init_tables<<<NCFG * 2, 256, 0, stream>>>(wtbl, itbl, ta);
    transpose_w<<<dim3(NCFG, BATCH), 256, 0, stream>>>(wp3, wp4, wp5, wT, tr);

    auto build = [&](int gstart, int gend, AggArgs& aa) -> int {
        aa.n = 0;
        int ablocks = 0;
        size_t off = 0;
        for (int c = gstart; c < gend; ++c) {
            ACfg& lc = aa.e[aa.n++];
            lc.kh = cfg[c].kh; lc.kw = cfg[c].kw; lc.kwp = cfg[c].kwp;
            lc.p0 = cfg[c].p0; lc.p1 = cfg[c].p1;
            lc.layer = cfg[c].layer;
            lc.ns = cfg[c].ns;
            lc.wt_off = cfg[c].wt_off;
            lc.ws_off = (int)off;
            lc.block_start = ablocks;
            lc.blocks_per_img = cfg[c].blocks_per_img;
            ablocks += cfg[c].blocks_per_img * BATCH;
            off += (size_t)cfg[c].kh * cfg[c].kwp * (BATCH * KK);
        }
        return ablocks;
    };
    auto gpx = [&](int gstart, int gend) -> size_t {
        size_t p = 0;
        for (int c = gstart; c < gend; ++c)
            p += (size_t)cfg[c].kh * cfg[c].kwp;
        return p * (BATCH * KK);
    };

    // New schedule: H={12..14} G1={0..11} G2={15..18} G3={19..20}.
    // A holds H then G2; B holds G1 then G3.
    size_t pxH = gpx(12, 15), px1 = gpx(0, 12), px2 = gpx(15, 19),
           px3 = gpx(19, 21);
    size_t pxA = pxH > px2 ? pxH : px2;
    size_t pxB = px1 > px3 ? px1 : px3;
    bool can_overlap =
        (size_t)AGG_OFF_BYTES + (pxA + pxB) * sizeof(uint2) <= ws_size;

    dim3 rgrid(14, 14, 16);

    if (can_overlap) {
        uint2* bufA = agg;
        uint2* bufB = agg + pxA;
        AggArgs aH, a1, a2, a3;
        int nH = build(12, 15, aH);
        int n1 = build(0, 12, a1);
        int n2 = build(15, 19, a2);
        int n3 = build(19, 21, a3);

        agg_all<<<nH, 256, 0, stream>>>(x, wT, bufA, aH);
        fused_k<12, 15><<<n1 + RZ_GRID, 256, 0, stream>>>(
            x, wT, bufB, a1, n1, bufA, wtbl, itbl, out, 0);
        fused_k<0, 12><<<n2 + RZ_GRID, 256, 0, stream>>>(
            x, wT, bufA, a2, n2, bufB, wtbl, itbl, out, 1);
        fused_k<15, 19><<<n3 + RZ_GRID, 256, 0, stream>>>(
            x, wT, bufB, a3, n3, bufA, wtbl, itbl, out, 1);
        resize_static<19, 21><<<rgrid, 256, 0, stream>>>(
            bufB, wtbl, itbl, out, 1);
    } else {
        // Serial fallback: same 4 groups, single buffer.
        AggArgs aa;
        int nb;
        nb = build(12, 15, aa);
        agg_all<<<nb, 256, 0, stream>>>(x, wT, agg, aa);
        resize_static<12, 15><<<rgrid, 256, 0, stream>>>(agg, wtbl, itbl, out, 0);
        nb = build(0, 12, aa);
        agg_all<<<nb, 256, 0, stream>>>(x, wT, agg, aa);
        resize_static<0, 12><<<rgrid, 256, 0, stream>>>(agg, wtbl, itbl, out, 1);
        nb = build(15, 19, aa);
        agg_all<<<nb, 256, 0, stream>>>(x, wT, agg, aa);
        resize_static<15, 19><<<rgrid, 256, 0, stream>>>(agg, wtbl, itbl, out, 1);
        nb = build(19, 21, aa);
        agg_all<<<nb, 256, 0, stream>>>(x, wT, agg, aa);
        resize_static<19, 21><<<rgrid, 256, 0, stream>>>(agg, wtbl, itbl, out, 1);
    }
    (void)in_sizes; (void)n_in; (void)out_size;
}